// Round 1
// baseline (8044.686 us; speedup 1.0000x reference)
//
#include <hip/hip_runtime.h>
#include <math.h>

// Problem constants: B=4096, W=H=64 (P=4096 pixels), F=1024, 50 AdamW steps.
// All GEMM dims are multiples of 64 -> no bounds guards needed.

__device__ __forceinline__ void mm_inner(const float (*As)[64], const float (*Bs)[64],
                                         float acc[4][4], int tx, int ty)
{
#pragma unroll
    for (int kk = 0; kk < 16; ++kk) {
        const float4 a = *(const float4*)(&As[kk][ty * 4]);
        const float4 b = *(const float4*)(&Bs[kk][tx * 4]);
        const float aa[4] = {a.x, a.y, a.z, a.w};
        const float bb[4] = {b.x, b.y, b.z, b.w};
#pragma unroll
        for (int i = 0; i < 4; ++i)
#pragma unroll
            for (int j = 0; j < 4; ++j)
                acc[i][j] = fmaf(aa[i], bb[j], acc[i][j]);
    }
}

// C[M,N] = A[M,K] @ B[K,N], all row-major.
__global__ __launch_bounds__(256) void gemm_nn(const float* __restrict__ A,
                                               const float* __restrict__ B,
                                               float* __restrict__ C,
                                               int M, int N, int K)
{
    __shared__ float As[16][64];  // [k][m]
    __shared__ float Bs[16][64];  // [k][n]
    const int t  = threadIdx.x;
    const int m0 = blockIdx.y * 64;
    const int n0 = blockIdx.x * 64;
    const int tx = t & 15, ty = t >> 4;
    const int ar = t >> 2, ac = (t & 3) * 4;   // A-tile: 64 rows x 16 k
    const int br = t >> 4, bc = (t & 15) * 4;  // B-tile: 16 k x 64 cols
    float acc[4][4] = {};
    for (int k0 = 0; k0 < K; k0 += 16) {
        float4 av = *(const float4*)(A + (size_t)(m0 + ar) * K + k0 + ac);
        float4 bv = *(const float4*)(B + (size_t)(k0 + br) * N + n0 + bc);
        As[ac + 0][ar] = av.x;
        As[ac + 1][ar] = av.y;
        As[ac + 2][ar] = av.z;
        As[ac + 3][ar] = av.w;
        *(float4*)(&Bs[br][bc]) = bv;
        __syncthreads();
        mm_inner(As, Bs, acc, tx, ty);
        __syncthreads();
    }
#pragma unroll
    for (int i = 0; i < 4; ++i) {
        float4 o = make_float4(acc[i][0], acc[i][1], acc[i][2], acc[i][3]);
        *(float4*)(C + (size_t)(m0 + ty * 4 + i) * N + n0 + tx * 4) = o;
    }
}

// C[N,N] = A^T @ A where A is [K,N] row-major (inhibit = Phi^T Phi).
__global__ __launch_bounds__(256) void gemm_ata(const float* __restrict__ A,
                                                float* __restrict__ C,
                                                int K, int N)
{
    __shared__ float As[16][64];
    __shared__ float Bs[16][64];
    const int t  = threadIdx.x;
    const int i0 = blockIdx.y * 64;
    const int j0 = blockIdx.x * 64;
    const int tx = t & 15, ty = t >> 4;
    const int br = t >> 4, bc = (t & 15) * 4;
    float acc[4][4] = {};
    for (int k0 = 0; k0 < K; k0 += 16) {
        *(float4*)(&As[br][bc]) = *(const float4*)(A + (size_t)(k0 + br) * N + i0 + bc);
        *(float4*)(&Bs[br][bc]) = *(const float4*)(A + (size_t)(k0 + br) * N + j0 + bc);
        __syncthreads();
        mm_inner(As, Bs, acc, tx, ty);
        __syncthreads();
    }
#pragma unroll
    for (int i = 0; i < 4; ++i) {
        float4 o = make_float4(acc[i][0], acc[i][1], acc[i][2], acc[i][3]);
        *(float4*)(C + (size_t)(i0 + ty * 4 + i) * N + j0 + tx * 4) = o;
    }
}

// C[M,N] = A[M,K] @ B[N,K]^T, row-major (recon = acts @ Phi^T).
__global__ __launch_bounds__(256) void gemm_nt(const float* __restrict__ A,
                                               const float* __restrict__ B,
                                               float* __restrict__ C,
                                               int M, int N, int K)
{
    __shared__ float As[16][64];
    __shared__ float Bs[16][64];
    const int t  = threadIdx.x;
    const int m0 = blockIdx.y * 64;
    const int n0 = blockIdx.x * 64;
    const int tx = t & 15, ty = t >> 4;
    const int ar = t >> 2, ac = (t & 3) * 4;
    float acc[4][4] = {};
    for (int k0 = 0; k0 < K; k0 += 16) {
        float4 av = *(const float4*)(A + (size_t)(m0 + ar) * K + k0 + ac);
        float4 bv = *(const float4*)(B + (size_t)(n0 + ar) * K + k0 + ac);
        As[ac + 0][ar] = av.x;
        As[ac + 1][ar] = av.y;
        As[ac + 2][ar] = av.z;
        As[ac + 3][ar] = av.w;
        Bs[ac + 0][ar] = bv.x;
        Bs[ac + 1][ar] = bv.y;
        Bs[ac + 2][ar] = bv.z;
        Bs[ac + 3][ar] = bv.w;
        __syncthreads();
        mm_inner(As, Bs, acc, tx, ty);
        __syncthreads();
    }
#pragma unroll
    for (int i = 0; i < 4; ++i) {
        float4 o = make_float4(acc[i][0], acc[i][1], acc[i][2], acc[i][3]);
        *(float4*)(C + (size_t)(m0 + ty * 4 + i) * N + n0 + tx * 4) = o;
    }
}

// One LCA/AdamW step fused: tmp = act_in @ G (M=4096,N=K=1024), then
// g = u - excite + tmp - act_in; AdamW update of (u,m,v); act_out = relu(u-0.25).
__global__ __launch_bounds__(256) void fused_step(const float* __restrict__ act_in,
                                                  const float* __restrict__ G,
                                                  const float* __restrict__ excite,
                                                  float* __restrict__ u,
                                                  float* __restrict__ m,
                                                  float* __restrict__ v,
                                                  float* __restrict__ act_out,
                                                  float inv_bc1, float inv_bc2)
{
    constexpr int N = 1024, K = 1024;
    __shared__ float As[16][64];
    __shared__ float Bs[16][64];
    const int t  = threadIdx.x;
    const int m0 = blockIdx.y * 64;
    const int n0 = blockIdx.x * 64;
    const int tx = t & 15, ty = t >> 4;
    const int ar = t >> 2, ac = (t & 3) * 4;
    const int br = t >> 4, bc = (t & 15) * 4;
    float acc[4][4] = {};
    for (int k0 = 0; k0 < K; k0 += 16) {
        float4 av = *(const float4*)(act_in + (size_t)(m0 + ar) * K + k0 + ac);
        float4 bv = *(const float4*)(G + (size_t)(k0 + br) * N + n0 + bc);
        As[ac + 0][ar] = av.x;
        As[ac + 1][ar] = av.y;
        As[ac + 2][ar] = av.z;
        As[ac + 3][ar] = av.w;
        *(float4*)(&Bs[br][bc]) = bv;
        __syncthreads();
        mm_inner(As, Bs, acc, tx, ty);
        __syncthreads();
    }
    const float lr = 0.1f, b1 = 0.9f, b2 = 0.999f, eps = 1e-8f;
    const float wdmul = 1.0f - lr * 1e-2f;  // decoupled weight decay
#pragma unroll
    for (int i = 0; i < 4; ++i) {
        const size_t base = (size_t)(m0 + ty * 4 + i) * N + n0 + tx * 4;
#pragma unroll
        for (int j = 0; j < 4; ++j) {
            const size_t idx = base + j;
            const float uold = u[idx];
            const float g  = uold - excite[idx] + acc[i][j] - act_in[idx];
            float uu = uold * wdmul;
            const float mm = b1 * m[idx] + (1.0f - b1) * g;
            const float vv = b2 * v[idx] + (1.0f - b2) * g * g;
            uu -= lr * (mm * inv_bc1) / (sqrtf(vv * inv_bc2) + eps);
            u[idx] = uu;
            m[idx] = mm;
            v[idx] = vv;
            act_out[idx] = fmaxf(uu - 0.25f, 0.0f);
        }
    }
}

extern "C" void kernel_launch(void* const* d_in, const int* in_sizes, int n_in,
                              void* d_out, int out_size, void* d_ws, size_t ws_size,
                              hipStream_t stream)
{
    const float* images  = (const float*)d_in[0];   // [4096, 64, 64] -> x [4096, 4096]
    const float* filters = (const float*)d_in[1];   // [64, 64, 1024] -> Phi [4096, 1024]
    float* out = (float*)d_out;                     // recon [4096*4096] then acts [4096*1024]

    constexpr size_t BF = (size_t)4096 * 1024;      // 4,194,304
    constexpr size_t PB = (size_t)4096 * 4096;      // 16,777,216 (recon elems)

    // Scratch placement:
    //   d_ws: excite [4096,1024], G [1024,1024]  (~21 MB)
    //   d_out recon region (dead until the end): u, m, v, actB
    //   d_out acts region: actA  (50 steps even -> final act lands here, no copy)
    float* excite = (float*)d_ws;
    float* G      = excite + BF;
    float* u      = out;            // [0 .. BF)
    float* m      = out + BF;       // [BF .. 2BF)
    float* v      = out + 2 * BF;   // [2BF .. 3BF)
    float* actB   = out + 3 * BF;   // [3BF .. 4BF)  (4BF == PB)
    float* actA   = out + PB;       // acts output slot

    hipMemsetAsync(u, 0, 3 * BF * sizeof(float), stream);     // u, m, v = 0
    hipMemsetAsync(actA, 0, BF * sizeof(float), stream);      // act_0 = 0

    dim3 blk(256);
    // excite = x @ Phi : [4096,4096] @ [4096,1024]
    gemm_nn<<<dim3(1024 / 64, 4096 / 64), blk, 0, stream>>>(images, filters, excite,
                                                            4096, 1024, 4096);
    // inhibit = Phi^T @ Phi : [1024,1024]
    gemm_ata<<<dim3(1024 / 64, 1024 / 64), blk, 0, stream>>>(filters, G, 4096, 1024);

    float* a_in  = actA;
    float* a_out = actB;
    for (int t = 1; t <= 50; ++t) {
        const float inv_bc1 = (float)(1.0 / (1.0 - pow(0.9, (double)t)));
        const float inv_bc2 = (float)(1.0 / (1.0 - pow(0.999, (double)t)));
        fused_step<<<dim3(1024 / 64, 4096 / 64), blk, 0, stream>>>(a_in, G, excite,
                                                                   u, m, v, a_out,
                                                                   inv_bc1, inv_bc2);
        float* tmp = a_in; a_in = a_out; a_out = tmp;
    }
    // After 50 swaps, a_in == actA == the acts output slot (final acts already there).

    // recon = acts @ Phi^T : [4096,1024] @ [1024,4096] -> overwrites u/m/v/actB (dead).
    gemm_nt<<<dim3(4096 / 64, 4096 / 64), blk, 0, stream>>>(a_in, filters, out,
                                                            4096, 4096, 1024);
}

// Round 2
// 3438.459 us; speedup vs baseline: 2.3396x; 2.3396x over previous
//
#include <hip/hip_runtime.h>
#include <math.h>

// B=4096 images, P=64*64=4096 pixels, F=1024 filters, 50 AdamW steps.
// All GEMMs as bf16 MFMA (16x16x32), fp32 accumulate, fp32 state.

typedef __bf16 bf16_t;
typedef __bf16 bf16x8 __attribute__((ext_vector_type(8)));
typedef __bf16 bf16x4 __attribute__((ext_vector_type(4)));
typedef float f32x4 __attribute__((ext_vector_type(4)));

__device__ __forceinline__ void async_ld16(const void* g, void* l) {
    __builtin_amdgcn_global_load_lds(
        (const __attribute__((address_space(1))) void*)g,
        (__attribute__((address_space(3))) void*)l, 16, 0, 0);
}

__global__ void cvt_bf16(const float* __restrict__ x, bf16_t* __restrict__ y, long n) {
    long i = ((long)blockIdx.x * blockDim.x + threadIdx.x) * 4;
    if (i + 3 < n) {
        float4 f = *(const float4*)(x + i);
        bf16x4 o = { (bf16_t)f.x, (bf16_t)f.y, (bf16_t)f.z, (bf16_t)f.w };
        *(bf16x4*)(y + i) = o;
    }
}

// PhiT[f][p] = Phi[p][f], fp32 -> bf16.  Phi is [4096,1024].
__global__ void transpose_cvt(const float* __restrict__ src, bf16_t* __restrict__ dst) {
    __shared__ float tile[32][33];
    const int f0 = blockIdx.x * 32;
    const int p0 = blockIdx.y * 32;
    const int tx = threadIdx.x, ty = threadIdx.y;
    for (int r = ty; r < 32; r += 8)
        tile[r][tx] = src[(size_t)(p0 + r) * 1024 + f0 + tx];
    __syncthreads();
    for (int r = ty; r < 32; r += 8)
        dst[(size_t)(f0 + r) * 4096 + p0 + tx] = (bf16_t)tile[tx][r];
}

// C[M,N] = A[M,K] @ BT[N,K]^T  (both bf16, K-major). 128x128 tile, BK=32,
// 256 threads = 4 waves in 2x2, each wave 64x64 via 4x4 of 16x16x32 MFMA.
// MODE 0: store C fp32.  MODE 1: store C bf16.  MODE 2: fused LCA/AdamW step.
template<int MODE>
__global__ __launch_bounds__(256) void gemm_bt(
    const bf16_t* __restrict__ A, const bf16_t* __restrict__ BT,
    int M, int N, int K,
    float* __restrict__ Cf, bf16_t* __restrict__ Cb,
    const float* __restrict__ excite,
    float* __restrict__ U, float* __restrict__ Mb, float* __restrict__ Vb,
    bf16_t* __restrict__ act_out, float* __restrict__ acts_f32,
    float inv_bc1, float inv_bc2)
{
    __shared__ bf16_t As[128 * 32];
    __shared__ bf16_t Bs[128 * 32];
    const int tid  = threadIdx.x;
    const int n0   = blockIdx.x * 128;
    const int m0   = blockIdx.y * 128;
    const int wave = tid >> 6;
    const int lane = tid & 63;
    const int wm   = (wave >> 1) * 64;
    const int wn   = (wave & 1) * 64;
    const int r0   = tid >> 2;          // staging row within half-tile
    const int kc   = (tid & 3) * 8;     // staging k offset (elements)
    const int lr   = lane >> 4;         // quad 0..3
    const int lc   = lane & 15;

    f32x4 acc[4][4] = {};

    const size_t arow0 = (size_t)(m0 + r0) * K;
    const size_t arow1 = (size_t)(m0 + 64 + r0) * K;
    const size_t brow0 = (size_t)(n0 + r0) * K;
    const size_t brow1 = (size_t)(n0 + 64 + r0) * K;

    for (int k0 = 0; k0 < K; k0 += 32) {
        // stage 128x32 A-tile and B-tile: LDS dest = wave base + lane*16 (required)
        async_ld16(A + arow0 + k0 + kc, &As[(size_t)tid * 8]);
        async_ld16(A + arow1 + k0 + kc, &As[(size_t)(tid + 256) * 8]);
        async_ld16(BT + brow0 + k0 + kc, &Bs[(size_t)tid * 8]);
        async_ld16(BT + brow1 + k0 + kc, &Bs[(size_t)(tid + 256) * 8]);
        __syncthreads();
        bf16x8 af[4], bv[4];
#pragma unroll
        for (int i = 0; i < 4; ++i) {
            af[i] = *(const bf16x8*)&As[(wm + i * 16 + lc) * 32 + lr * 8];
            bv[i] = *(const bf16x8*)&Bs[(wn + i * 16 + lc) * 32 + lr * 8];
        }
#pragma unroll
        for (int i = 0; i < 4; ++i)
#pragma unroll
            for (int j = 0; j < 4; ++j)
                acc[i][j] = __builtin_amdgcn_mfma_f32_16x16x32_bf16(af[i], bv[j], acc[i][j], 0, 0, 0);
        __syncthreads();
    }

    // C/D layout (m89-verified): col = lane&15, row = (lane>>4)*4 + reg
    if constexpr (MODE == 0) {
#pragma unroll
        for (int i = 0; i < 4; ++i)
#pragma unroll
            for (int t = 0; t < 4; ++t) {
                const size_t row = (size_t)(m0 + wm + i * 16 + lr * 4 + t);
#pragma unroll
                for (int j = 0; j < 4; ++j)
                    Cf[row * N + n0 + wn + j * 16 + lc] = acc[i][j][t];
            }
    } else if constexpr (MODE == 1) {
#pragma unroll
        for (int i = 0; i < 4; ++i)
#pragma unroll
            for (int t = 0; t < 4; ++t) {
                const size_t row = (size_t)(m0 + wm + i * 16 + lr * 4 + t);
#pragma unroll
                for (int j = 0; j < 4; ++j)
                    Cb[row * N + n0 + wn + j * 16 + lc] = (bf16_t)acc[i][j][t];
            }
    } else {
        // g = u - excite + (act@G) - act ; AdamW ; act_out = relu(u'-0.25)
        const float lrate = 0.1f, b1 = 0.9f, b2 = 0.999f, eps = 1e-8f;
        const float wdmul = 1.0f - lrate * 1e-2f;
#pragma unroll
        for (int i = 0; i < 4; ++i)
#pragma unroll
            for (int t = 0; t < 4; ++t) {
                const size_t base = (size_t)(m0 + wm + i * 16 + lr * 4 + t) * 1024;
#pragma unroll
                for (int j = 0; j < 4; ++j) {
                    const size_t idx = base + n0 + wn + j * 16 + lc;
                    const float uold = U[idx];
                    const float act  = fmaxf(uold - 0.25f, 0.0f);
                    const float g    = uold - excite[idx] + acc[i][j][t] - act;
                    const float mm   = b1 * Mb[idx] + (1.0f - b1) * g;
                    const float vv   = b2 * Vb[idx] + (1.0f - b2) * g * g;
                    float uu = uold * wdmul;
                    uu -= lrate * (mm * inv_bc1) / (sqrtf(vv * inv_bc2) + eps);
                    U[idx]  = uu;
                    Mb[idx] = mm;
                    Vb[idx] = vv;
                    const float anew = fmaxf(uu - 0.25f, 0.0f);
                    act_out[idx] = (bf16_t)anew;
                    if (acts_f32) acts_f32[idx] = anew;
                }
            }
    }
}

extern "C" void kernel_launch(void* const* d_in, const int* in_sizes, int n_in,
                              void* d_out, int out_size, void* d_ws, size_t ws_size,
                              hipStream_t stream)
{
    const float* images  = (const float*)d_in[0];   // [4096, 4096] (B x P)
    const float* filters = (const float*)d_in[1];   // [4096, 1024] (P x F)
    float* out = (float*)d_out;

    constexpr int B = 4096, P = 4096, F = 1024;
    constexpr size_t BF = (size_t)B * F;   // 4M
    constexpr size_t BP = (size_t)B * P;   // 16M

    // d_out (20M floats) time-shared:
    //   [0,8M)  : xbf (16M bf16) -> later m,v (fp32)
    //   [8M,12M): excite fp32
    //   [12M,16M): u fp32              (recon overwrites [0,16M) at the end)
    //   [16M,20M): acts output (written in step 50)
    bf16_t* xbf   = (bf16_t*)out;
    float*  mbuf  = out;
    float*  vbuf  = out + BF;
    float*  excite= out + 2 * BF;
    float*  ubuf  = out + 3 * BF;
    float*  actsf = out + BP;

    // ws (18 MB): w0 = phiT then act0 ; w1 = actB then phibf ; Gbf
    bf16_t* w0  = (bf16_t*)d_ws;
    bf16_t* w1  = w0 + BF;
    bf16_t* Gbf = w1 + BF;

    dim3 blk(256);
    // 1. x -> bf16 (into d_out scratch)
    cvt_bf16<<<(unsigned)(BP / 4 / 256), blk, 0, stream>>>(images, xbf, (long)BP);
    // 2. PhiT bf16 [F,P]
    transpose_cvt<<<dim3(F / 32, P / 32), dim3(32, 8), 0, stream>>>(filters, w0);
    // 3. excite = x @ Phi : A=xbf [B,P], BT=phiT [F,P] -> fp32 [B,F]
    gemm_bt<0><<<dim3(F / 128, B / 128), blk, 0, stream>>>(
        xbf, w0, B, F, P, excite, nullptr, nullptr, nullptr, nullptr, nullptr,
        nullptr, nullptr, 0.f, 0.f);
    // 4. G = PhiT @ Phi : A=phiT [F,P], BT=phiT [F,P] -> bf16 [F,F] (symmetric)
    gemm_bt<1><<<dim3(F / 128, F / 128), blk, 0, stream>>>(
        w0, w0, F, F, P, nullptr, Gbf, nullptr, nullptr, nullptr, nullptr,
        nullptr, nullptr, 0.f, 0.f);
    // 5. zero state (xbf and phiT now dead)
    hipMemsetAsync(mbuf, 0, 2 * BF * sizeof(float), stream);  // m, v
    hipMemsetAsync(ubuf, 0, BF * sizeof(float), stream);      // u
    hipMemsetAsync(w0, 0, BF * sizeof(bf16_t), stream);       // act_0 = 0
    // 6. 50 fused LCA/AdamW steps: tmp = act@G, update, act' = relu(u-0.25)
    bf16_t* a_in = w0;
    bf16_t* a_out = w1;
    for (int t = 1; t <= 50; ++t) {
        const float inv_bc1 = (float)(1.0 / (1.0 - pow(0.9, (double)t)));
        const float inv_bc2 = (float)(1.0 / (1.0 - pow(0.999, (double)t)));
        gemm_bt<2><<<dim3(F / 128, B / 128), blk, 0, stream>>>(
            a_in, Gbf, B, F, F, nullptr, nullptr, excite, ubuf, mbuf, vbuf,
            a_out, (t == 50) ? actsf : nullptr, inv_bc1, inv_bc2);
        bf16_t* tmp = a_in; a_in = a_out; a_out = tmp;
    }
    // after 50 swaps a_in == w0 holds final bf16 acts; w1 is dead
    // 7. Phi bf16 [P,F] (into w1)
    cvt_bf16<<<(unsigned)(BF / 4 / 256), blk, 0, stream>>>(filters, w1, (long)BF);
    // 8. recon = acts @ Phi^T : A=acts [B,F], BT=phibf [P,F] -> fp32 [B,P]
    gemm_bt<0><<<dim3(P / 128, B / 128), blk, 0, stream>>>(
        a_in, w1, B, P, F, out, nullptr, nullptr, nullptr, nullptr, nullptr,
        nullptr, nullptr, 0.f, 0.f);
}

// Round 4
// 3170.440 us; speedup vs baseline: 2.5374x; 1.0845x over previous
//
#include <hip/hip_runtime.h>
#include <math.h>

// B=4096 images, P=4096 pixels, F=1024 filters, 50 AdamW steps.
// Round 3 (fix compile): persistent LCA kernel — state in registers, act in
// LDS, G streamed from L2 (blocked layout) straight into MFMA B-fragments.

typedef __bf16 bf16_t;
typedef __bf16 bf16x8 __attribute__((ext_vector_type(8)));
typedef __bf16 bf16x4 __attribute__((ext_vector_type(4)));
typedef float f32x4 __attribute__((ext_vector_type(4)));

__device__ __forceinline__ void async_ld16(const void* g, void* l) {
    __builtin_amdgcn_global_load_lds(
        (const __attribute__((address_space(1))) void*)g,
        (__attribute__((address_space(3))) void*)l, 16, 0, 0);
}

__global__ void cvt_bf16(const float* __restrict__ x, bf16_t* __restrict__ y, long n) {
    long i = ((long)blockIdx.x * blockDim.x + threadIdx.x) * 4;
    if (i + 3 < n) {
        float4 f = *(const float4*)(x + i);
        bf16x4 o = { (bf16_t)f.x, (bf16_t)f.y, (bf16_t)f.z, (bf16_t)f.w };
        *(bf16x4*)(y + i) = o;
    }
}

// PhiT[f][p] = Phi[p][f], fp32 -> bf16.  Phi is [4096,1024].
__global__ void transpose_cvt(const float* __restrict__ src, bf16_t* __restrict__ dst) {
    __shared__ float tile[32][33];
    const int f0 = blockIdx.x * 32;
    const int p0 = blockIdx.y * 32;
    const int tx = threadIdx.x, ty = threadIdx.y;
    for (int r = ty; r < 32; r += 8)
        tile[r][tx] = src[(size_t)(p0 + r) * 1024 + f0 + tx];
    __syncthreads();
    for (int r = ty; r < 32; r += 8)
        dst[(size_t)(f0 + r) * 4096 + p0 + tx] = (bf16_t)tile[tx][r];
}

// C[M,N] = A[M,K] @ BT[N,K]^T (bf16, K-major). 128x128 tile, BK=32.
// MODE 0: store C fp32.  MODE 3: store C bf16 in blocked layout
//   Gblk[row/32][col][row%32]  (requires N==1024).
template<int MODE>
__global__ __launch_bounds__(256) void gemm_bt(
    const bf16_t* __restrict__ A, const bf16_t* __restrict__ BT,
    int M, int N, int K,
    float* __restrict__ Cf, bf16_t* __restrict__ Cb)
{
    __shared__ bf16_t As[128 * 32];
    __shared__ bf16_t Bs[128 * 32];
    const int tid  = threadIdx.x;
    const int n0   = blockIdx.x * 128;
    const int m0   = blockIdx.y * 128;
    const int wave = tid >> 6;
    const int lane = tid & 63;
    const int wm   = (wave >> 1) * 64;
    const int wn   = (wave & 1) * 64;
    const int r0   = tid >> 2;
    const int kc   = (tid & 3) * 8;
    const int lr   = lane >> 4;
    const int lc   = lane & 15;

    f32x4 acc[4][4] = {};
    const size_t arow0 = (size_t)(m0 + r0) * K;
    const size_t arow1 = (size_t)(m0 + 64 + r0) * K;
    const size_t brow0 = (size_t)(n0 + r0) * K;
    const size_t brow1 = (size_t)(n0 + 64 + r0) * K;

    for (int k0 = 0; k0 < K; k0 += 32) {
        async_ld16(A + arow0 + k0 + kc, &As[(size_t)tid * 8]);
        async_ld16(A + arow1 + k0 + kc, &As[(size_t)(tid + 256) * 8]);
        async_ld16(BT + brow0 + k0 + kc, &Bs[(size_t)tid * 8]);
        async_ld16(BT + brow1 + k0 + kc, &Bs[(size_t)(tid + 256) * 8]);
        __syncthreads();
        bf16x8 af[4], bv[4];
#pragma unroll
        for (int i = 0; i < 4; ++i) {
            af[i] = *(const bf16x8*)&As[(wm + i * 16 + lc) * 32 + lr * 8];
            bv[i] = *(const bf16x8*)&Bs[(wn + i * 16 + lc) * 32 + lr * 8];
        }
#pragma unroll
        for (int i = 0; i < 4; ++i)
#pragma unroll
            for (int j = 0; j < 4; ++j)
                acc[i][j] = __builtin_amdgcn_mfma_f32_16x16x32_bf16(af[i], bv[j], acc[i][j], 0, 0, 0);
        __syncthreads();
    }

    // C/D layout: col = lane&15, row = (lane>>4)*4 + reg
#pragma unroll
    for (int i = 0; i < 4; ++i)
#pragma unroll
        for (int t = 0; t < 4; ++t) {
            const int row = m0 + wm + i * 16 + lr * 4 + t;
#pragma unroll
            for (int j = 0; j < 4; ++j) {
                const int col = n0 + wn + j * 16 + lc;
                if constexpr (MODE == 0) {
                    Cf[(size_t)row * N + col] = acc[i][j][t];
                } else {
                    Cb[(size_t)(((row >> 5) << 10) + col) * 32 + (row & 31)] =
                        (bf16_t)acc[i][j][t];
                }
            }
        }
}

// Persistent LCA: each block owns 16 rows for all 50 steps.
// 512 threads = 8 waves; wave w covers cols [w*128, w*128+128) (8 n-tiles).
// State (u,m,v,excite) in registers; act bf16 in LDS (swizzled);
// G read from L2 via blocked layout Gblk[k/32][n][k%32].
__global__ __launch_bounds__(512, 2) void lca_persistent(
    const bf16_t* __restrict__ Gblk, const float* __restrict__ excite,
    float* __restrict__ actsf, bf16_t* __restrict__ actbf)
{
    __shared__ bf16_t act[16 * 1024];   // 32 KB; 16B units swizzled: unit ^= (row&7)
    const int tid  = threadIdx.x;
    const int m0   = blockIdx.x * 16;
    const int wave = tid >> 6;
    const int lane = tid & 63;
    const int lr   = lane >> 4;
    const int lc   = lane & 15;
    const int wn   = wave * 128;

    // zero act buffer (act_1 = relu(0 - 0.25) = 0)
    for (int i = tid; i < 16 * 1024 / 8; i += 512) {
        bf16x8 z = {};
        *(bf16x8*)&act[i * 8] = z;
    }

    f32x4 U[8] = {}, Mo[8] = {}, Vo[8] = {}, EX[8];
#pragma unroll
    for (int j = 0; j < 8; ++j)
#pragma unroll
        for (int t = 0; t < 4; ++t)
            EX[j][t] = excite[(size_t)(m0 + lr * 4 + t) * 1024 + wn + j * 16 + lc];
    __syncthreads();

    const float lrate = 0.1f, b1 = 0.9f, b2 = 0.999f, eps = 1e-8f;
    const float wdmul = 1.0f - lrate * 1e-2f;
    float pb1 = 1.0f, pb2 = 1.0f;

    for (int step = 1; step <= 50; ++step) {
        pb1 *= b1; pb2 *= b2;
        const float inv1 = 1.0f / (1.0f - pb1);
        const float inv2 = 1.0f / (1.0f - pb2);

        f32x4 acc[8] = {};
        for (int kcb = 0; kcb < 32; ++kcb) {
            // A-fragment: act[m = lc][k = kcb*32 + lr*8 + 0..7], swizzled
            const int unit = kcb * 4 + lr;
            const bf16x8 a = *(const bf16x8*)&act[lc * 1024 + ((unit ^ (lc & 7)) << 3)];
            bf16x8 b[8];
#pragma unroll
            for (int j = 0; j < 8; ++j)
                b[j] = *(const bf16x8*)(Gblk +
                        (size_t)(((kcb << 10) + wn + j * 16 + lc) << 5) + lr * 8);
#pragma unroll
            for (int j = 0; j < 8; ++j)
                acc[j] = __builtin_amdgcn_mfma_f32_16x16x32_bf16(a, b[j], acc[j], 0, 0, 0);
        }
        __syncthreads();   // all waves done reading act

#pragma unroll
        for (int j = 0; j < 8; ++j)
#pragma unroll
            for (int t = 0; t < 4; ++t) {
                const int row = lr * 4 + t;
                const int col = wn + j * 16 + lc;
                const float uold = U[j][t];
                const float aold = fmaxf(uold - 0.25f, 0.0f);
                const float g    = uold - EX[j][t] + acc[j][t] - aold;
                const float mn   = b1 * Mo[j][t] + (1.0f - b1) * g;
                const float vn   = b2 * Vo[j][t] + (1.0f - b2) * g * g;
                float un = uold * wdmul;
                un -= lrate * (mn * inv1) / (sqrtf(vn * inv2) + eps);
                U[j][t] = un; Mo[j][t] = mn; Vo[j][t] = vn;
                const float an = fmaxf(un - 0.25f, 0.0f);
                const int su = (col >> 3) ^ (row & 7);
                act[row * 1024 + (su << 3) + (col & 7)] = (bf16_t)an;
                if (step == 50) {
                    actsf[(size_t)(m0 + row) * 1024 + col] = an;
                    actbf[(size_t)(m0 + row) * 1024 + col] = (bf16_t)an;
                }
            }
        __syncthreads();   // act ready for next step
    }
}

extern "C" void kernel_launch(void* const* d_in, const int* in_sizes, int n_in,
                              void* d_out, int out_size, void* d_ws, size_t ws_size,
                              hipStream_t stream)
{
    const float* images  = (const float*)d_in[0];   // [4096, 4096] (B x P)
    const float* filters = (const float*)d_in[1];   // [4096, 1024] (P x F)
    float* out = (float*)d_out;

    constexpr int B = 4096, P = 4096, F = 1024;
    constexpr size_t BF = (size_t)B * F;   // 4M elems
    constexpr size_t BP = (size_t)B * P;   // 16M elems

    // d_out (80 MB) time-shared:
    //   out[0 : 8M floats)   : xbf (16M bf16)          -> recon overwrites later
    //   out[8M : 12M floats) : excite fp32             -> recon overwrites later
    //   out[16M : 20M floats): acts output (persistent kernel writes it)
    bf16_t* xbf    = (bf16_t*)out;
    float*  excite = out + 2 * BF;
    float*  actsf  = out + BP;

    // d_ws (18 MB): w0 = phiT (8 MB) then actbf ; Gblk (2 MB) ; phibf (8 MB)
    bf16_t* w0    = (bf16_t*)d_ws;
    bf16_t* Gblk  = w0 + BF;               // +8 MB
    bf16_t* phibf = w0 + BF + BF / 4;      // +10 MB

    dim3 blk(256);
    // 1. x -> bf16
    cvt_bf16<<<(unsigned)(BP / 4 / 256), blk, 0, stream>>>(images, xbf, (long)BP);
    // 2. PhiT bf16 [F,P]
    transpose_cvt<<<dim3(F / 32, P / 32), dim3(32, 8), 0, stream>>>(filters, w0);
    // 3. excite = x @ Phi  (A=xbf [B,P], BT=phiT [F,P]) -> fp32 [B,F]
    gemm_bt<0><<<dim3(F / 128, B / 128), blk, 0, stream>>>(
        xbf, w0, B, F, P, excite, nullptr);
    // 4. G = PhiT @ Phi -> blocked bf16 Gblk[k/32][n][k%32]
    gemm_bt<3><<<dim3(F / 128, F / 128), blk, 0, stream>>>(
        w0, w0, F, F, P, nullptr, Gblk);
    // 5. 50 LCA/AdamW steps, persistent. Writes acts fp32 (d_out) + actbf (w0).
    lca_persistent<<<dim3(B / 16), dim3(512), 0, stream>>>(Gblk, excite, actsf, w0);
    // 6. Phi -> bf16 [P,F]
    cvt_bf16<<<(unsigned)(BF / 4 / 256), blk, 0, stream>>>(filters, phibf, (long)BF);
    // 7. recon = acts @ Phi^T (A=actbf [B,F], BT=phibf [P,F]) -> fp32 [B,P]
    gemm_bt<0><<<dim3(P / 128, B / 128), blk, 0, stream>>>(
        w0, phibf, B, P, F, out, nullptr);
}

// Round 5
// 3168.764 us; speedup vs baseline: 2.5387x; 1.0005x over previous
//
#include <hip/hip_runtime.h>
#include <math.h>

// B=4096 images, P=4096 pixels, F=1024 filters, 50 AdamW steps.
// Round 5: fix VGPR cap (was __launch_bounds__(512,2) -> 128 regs -> ~2GB
// scratch spill traffic). Now waves_per_eu(2) -> 256-reg budget, no spill.

typedef __bf16 bf16_t;
typedef __bf16 bf16x8 __attribute__((ext_vector_type(8)));
typedef __bf16 bf16x4 __attribute__((ext_vector_type(4)));
typedef float f32x4 __attribute__((ext_vector_type(4)));

__device__ __forceinline__ void async_ld16(const void* g, void* l) {
    __builtin_amdgcn_global_load_lds(
        (const __attribute__((address_space(1))) void*)g,
        (__attribute__((address_space(3))) void*)l, 16, 0, 0);
}

__global__ void cvt_bf16(const float* __restrict__ x, bf16_t* __restrict__ y, long n) {
    long i = ((long)blockIdx.x * blockDim.x + threadIdx.x) * 4;
    if (i + 3 < n) {
        float4 f = *(const float4*)(x + i);
        bf16x4 o = { (bf16_t)f.x, (bf16_t)f.y, (bf16_t)f.z, (bf16_t)f.w };
        *(bf16x4*)(y + i) = o;
    }
}

// PhiT[f][p] = Phi[p][f], fp32 -> bf16.  Phi is [4096,1024].
__global__ void transpose_cvt(const float* __restrict__ src, bf16_t* __restrict__ dst) {
    __shared__ float tile[32][33];
    const int f0 = blockIdx.x * 32;
    const int p0 = blockIdx.y * 32;
    const int tx = threadIdx.x, ty = threadIdx.y;
    for (int r = ty; r < 32; r += 8)
        tile[r][tx] = src[(size_t)(p0 + r) * 1024 + f0 + tx];
    __syncthreads();
    for (int r = ty; r < 32; r += 8)
        dst[(size_t)(f0 + r) * 4096 + p0 + tx] = (bf16_t)tile[tx][r];
}

// C[M,N] = A[M,K] @ BT[N,K]^T (bf16, K-major). 128x128 tile, BK=32.
// MODE 0: store C fp32.  MODE 3: store C bf16 in blocked layout
//   Gblk[row/32][col][row%32]  (requires N==1024).
template<int MODE>
__global__ __launch_bounds__(256) void gemm_bt(
    const bf16_t* __restrict__ A, const bf16_t* __restrict__ BT,
    int M, int N, int K,
    float* __restrict__ Cf, bf16_t* __restrict__ Cb)
{
    __shared__ bf16_t As[128 * 32];
    __shared__ bf16_t Bs[128 * 32];
    const int tid  = threadIdx.x;
    const int n0   = blockIdx.x * 128;
    const int m0   = blockIdx.y * 128;
    const int wave = tid >> 6;
    const int lane = tid & 63;
    const int wm   = (wave >> 1) * 64;
    const int wn   = (wave & 1) * 64;
    const int r0   = tid >> 2;
    const int kc   = (tid & 3) * 8;
    const int lr   = lane >> 4;
    const int lc   = lane & 15;

    f32x4 acc[4][4] = {};
    const size_t arow0 = (size_t)(m0 + r0) * K;
    const size_t arow1 = (size_t)(m0 + 64 + r0) * K;
    const size_t brow0 = (size_t)(n0 + r0) * K;
    const size_t brow1 = (size_t)(n0 + 64 + r0) * K;

    for (int k0 = 0; k0 < K; k0 += 32) {
        async_ld16(A + arow0 + k0 + kc, &As[(size_t)tid * 8]);
        async_ld16(A + arow1 + k0 + kc, &As[(size_t)(tid + 256) * 8]);
        async_ld16(BT + brow0 + k0 + kc, &Bs[(size_t)tid * 8]);
        async_ld16(BT + brow1 + k0 + kc, &Bs[(size_t)(tid + 256) * 8]);
        __syncthreads();
        bf16x8 af[4], bv[4];
#pragma unroll
        for (int i = 0; i < 4; ++i) {
            af[i] = *(const bf16x8*)&As[(wm + i * 16 + lc) * 32 + lr * 8];
            bv[i] = *(const bf16x8*)&Bs[(wn + i * 16 + lc) * 32 + lr * 8];
        }
#pragma unroll
        for (int i = 0; i < 4; ++i)
#pragma unroll
            for (int j = 0; j < 4; ++j)
                acc[i][j] = __builtin_amdgcn_mfma_f32_16x16x32_bf16(af[i], bv[j], acc[i][j], 0, 0, 0);
        __syncthreads();
    }

    // C/D layout: col = lane&15, row = (lane>>4)*4 + reg
#pragma unroll
    for (int i = 0; i < 4; ++i)
#pragma unroll
        for (int t = 0; t < 4; ++t) {
            const int row = m0 + wm + i * 16 + lr * 4 + t;
#pragma unroll
            for (int j = 0; j < 4; ++j) {
                const int col = n0 + wn + j * 16 + lc;
                if constexpr (MODE == 0) {
                    Cf[(size_t)row * N + col] = acc[i][j][t];
                } else {
                    Cb[(size_t)(((row >> 5) << 10) + col) * 32 + (row & 31)] =
                        (bf16_t)acc[i][j][t];
                }
            }
        }
}

// Persistent LCA: each block owns 16 rows for all 50 steps.
// 512 threads = 8 waves; wave w covers cols [w*128, w*128+128) (8 n-tiles).
// State (u,m,v,excite) in registers (~210 VGPRs); act bf16 in LDS (swizzled);
// G read from L2 via blocked layout Gblk[k/32][n][k%32].
// waves_per_eu(2): 256-VGPR budget so the ~210-reg working set does NOT spill
// (launch_bounds(512,2) previously capped at 128 -> 2GB scratch traffic).
__global__ __launch_bounds__(512) __attribute__((amdgpu_waves_per_eu(2)))
void lca_persistent(
    const bf16_t* __restrict__ Gblk, const float* __restrict__ excite,
    float* __restrict__ actsf, bf16_t* __restrict__ actbf)
{
    __shared__ bf16_t act[16 * 1024];   // 32 KB; 16B units swizzled: unit ^= (row&7)
    const int tid  = threadIdx.x;
    const int m0   = blockIdx.x * 16;
    const int wave = tid >> 6;
    const int lane = tid & 63;
    const int lr   = lane >> 4;
    const int lc   = lane & 15;
    const int wn   = wave * 128;

    // zero act buffer (act_1 = relu(0 - 0.25) = 0)
    for (int i = tid; i < 16 * 1024 / 8; i += 512) {
        bf16x8 z = {};
        *(bf16x8*)&act[i * 8] = z;
    }

    f32x4 U[8] = {}, Mo[8] = {}, Vo[8] = {}, EX[8];
#pragma unroll
    for (int j = 0; j < 8; ++j)
#pragma unroll
        for (int t = 0; t < 4; ++t)
            EX[j][t] = excite[(size_t)(m0 + lr * 4 + t) * 1024 + wn + j * 16 + lc];
    __syncthreads();

    const float lrate = 0.1f, b1 = 0.9f, b2 = 0.999f, eps = 1e-8f;
    const float wdmul = 1.0f - lrate * 1e-2f;
    float pb1 = 1.0f, pb2 = 1.0f;

    for (int step = 1; step <= 50; ++step) {
        pb1 *= b1; pb2 *= b2;
        const float inv1 = 1.0f / (1.0f - pb1);
        const float inv2 = 1.0f / (1.0f - pb2);

        f32x4 acc[8] = {};
#pragma unroll 2
        for (int kcb = 0; kcb < 32; ++kcb) {
            // A-fragment: act[m = lc][k = kcb*32 + lr*8 + 0..7], swizzled
            const int unit = kcb * 4 + lr;
            const bf16x8 a = *(const bf16x8*)&act[lc * 1024 + ((unit ^ (lc & 7)) << 3)];
            bf16x8 b[8];
#pragma unroll
            for (int j = 0; j < 8; ++j)
                b[j] = *(const bf16x8*)(Gblk +
                        (size_t)(((kcb << 10) + wn + j * 16 + lc) << 5) + lr * 8);
#pragma unroll
            for (int j = 0; j < 8; ++j)
                acc[j] = __builtin_amdgcn_mfma_f32_16x16x32_bf16(a, b[j], acc[j], 0, 0, 0);
        }
        __syncthreads();   // all waves done reading act

#pragma unroll
        for (int j = 0; j < 8; ++j)
#pragma unroll
            for (int t = 0; t < 4; ++t) {
                const int row = lr * 4 + t;
                const int col = wn + j * 16 + lc;
                const float uold = U[j][t];
                const float aold = fmaxf(uold - 0.25f, 0.0f);
                const float g    = uold - EX[j][t] + acc[j][t] - aold;
                const float mn   = b1 * Mo[j][t] + (1.0f - b1) * g;
                const float vn   = b2 * Vo[j][t] + (1.0f - b2) * g * g;
                float un = uold * wdmul;
                un -= lrate * (mn * inv1) / (sqrtf(vn * inv2) + eps);
                U[j][t] = un; Mo[j][t] = mn; Vo[j][t] = vn;
                const float an = fmaxf(un - 0.25f, 0.0f);
                const int su = (col >> 3) ^ (row & 7);
                act[row * 1024 + (su << 3) + (col & 7)] = (bf16_t)an;
                if (step == 50) {
                    actsf[(size_t)(m0 + row) * 1024 + col] = an;
                    actbf[(size_t)(m0 + row) * 1024 + col] = (bf16_t)an;
                }
            }
        __syncthreads();   // act ready for next step
    }
}

extern "C" void kernel_launch(void* const* d_in, const int* in_sizes, int n_in,
                              void* d_out, int out_size, void* d_ws, size_t ws_size,
                              hipStream_t stream)
{
    const float* images  = (const float*)d_in[0];   // [4096, 4096] (B x P)
    const float* filters = (const float*)d_in[1];   // [4096, 1024] (P x F)
    float* out = (float*)d_out;

    constexpr int B = 4096, P = 4096, F = 1024;
    constexpr size_t BF = (size_t)B * F;   // 4M elems
    constexpr size_t BP = (size_t)B * P;   // 16M elems

    // d_out (80 MB) time-shared:
    //   out[0 : 8M floats)   : xbf (16M bf16)          -> recon overwrites later
    //   out[8M : 12M floats) : excite fp32             -> recon overwrites later
    //   out[16M : 20M floats): acts output (persistent kernel writes it)
    bf16_t* xbf    = (bf16_t*)out;
    float*  excite = out + 2 * BF;
    float*  actsf  = out + BP;

    // d_ws (18 MB): w0 = phiT (8 MB) then actbf ; Gblk (2 MB) ; phibf (8 MB)
    bf16_t* w0    = (bf16_t*)d_ws;
    bf16_t* Gblk  = w0 + BF;               // +8 MB
    bf16_t* phibf = w0 + BF + BF / 4;      // +10 MB

    dim3 blk(256);
    // 1. x -> bf16
    cvt_bf16<<<(unsigned)(BP / 4 / 256), blk, 0, stream>>>(images, xbf, (long)BP);
    // 2. PhiT bf16 [F,P]
    transpose_cvt<<<dim3(F / 32, P / 32), dim3(32, 8), 0, stream>>>(filters, w0);
    // 3. excite = x @ Phi  (A=xbf [B,P], BT=phiT [F,P]) -> fp32 [B,F]
    gemm_bt<0><<<dim3(F / 128, B / 128), blk, 0, stream>>>(
        xbf, w0, B, F, P, excite, nullptr);
    // 4. G = PhiT @ Phi -> blocked bf16 Gblk[k/32][n][k%32]
    gemm_bt<3><<<dim3(F / 128, F / 128), blk, 0, stream>>>(
        w0, w0, F, F, P, nullptr, Gblk);
    // 5. 50 LCA/AdamW steps, persistent. Writes acts fp32 (d_out) + actbf (w0).
    lca_persistent<<<dim3(B / 16), dim3(512), 0, stream>>>(Gblk, excite, actsf, w0);
    // 6. Phi -> bf16 [P,F]
    cvt_bf16<<<(unsigned)(BF / 4 / 256), blk, 0, stream>>>(filters, phibf, (long)BF);
    // 7. recon = acts @ Phi^T (A=actbf [B,F], BT=phibf [P,F]) -> fp32 [B,P]
    gemm_bt<0><<<dim3(P / 128, B / 128), blk, 0, stream>>>(
        w0, phibf, B, P, F, out, nullptr);
}